// Round 8
// baseline (1858.565 us; speedup 1.0000x reference)
//
#include <hip/hip_runtime.h>

#define T_LEN 2050
#define B_SZ 128
#define NCHUNK 33               // chunks of steps t=1..2049
#define HL2PI 0.91893853320467274178f

// ---------- wave-wide helpers (wave = 64 lanes) ----------
__device__ __forceinline__ float waveMax(float v) {
#pragma unroll
    for (int off = 32; off >= 1; off >>= 1)
        v = fmaxf(v, __shfl_xor(v, off, 64));
    return v;
}
__device__ __forceinline__ float waveSum(float v) {
#pragma unroll
    for (int off = 32; off >= 1; off >>= 1)
        v += __shfl_xor(v, off, 64);
    return v;
}
__device__ __forceinline__ void waveArgmax(float& v, int& idx) {
#pragma unroll
    for (int off = 32; off >= 1; off >>= 1) {
        float ov = __shfl_xor(v, off, 64);
        int   oi = __shfl_xor(idx, off, 64);
        if (ov > v || (ov == v && oi < idx)) { v = ov; idx = oi; }
    }
}
__device__ __forceinline__ void cfence() { asm volatile("" ::: "memory"); }

// DPP full-wave reductions (rounds 5-7 proven)
__device__ __forceinline__ float dppSumAll(float v) {
#define SSTEP(ctrl) { int t_ = __builtin_amdgcn_update_dpp(0, __float_as_int(v), ctrl, 0xf, 0xf, true); \
                      v = v + __int_as_float(t_); }
    SSTEP(0x111) SSTEP(0x112) SSTEP(0x114) SSTEP(0x118) SSTEP(0x142) SSTEP(0x143)
#undef SSTEP
    return __int_as_float(__builtin_amdgcn_readlane(__float_as_int(v), 63));
}
__device__ __forceinline__ float dppMaxAll(float v) {
#define MSTEP(ctrl) { int t_ = __builtin_amdgcn_update_dpp(__float_as_int(v), __float_as_int(v), ctrl, 0xf, 0xf, false); \
                      v = fmaxf(v, __int_as_float(t_)); }
    MSTEP(0x111) MSTEP(0x112) MSTEP(0x114) MSTEP(0x118) MSTEP(0x142) MSTEP(0x143)
#undef MSTEP
    return __int_as_float(__builtin_amdgcn_readlane(__float_as_int(v), 63));
}

// ===== prep: log_softmax(log_A) -> lAg[c*64+i] (column-major), log_softmax(log_pi) =====
extern "C" __global__ __launch_bounds__(64, 1)
void hmm_prep(const float* __restrict__ logA_in,
              const float* __restrict__ logpi_in,
              float* __restrict__ lAg,
              float* __restrict__ lpig)
{
    __shared__ float la[64 * 65];
    __shared__ float rowlse[64];
    const int j = threadIdx.x;
#pragma unroll
    for (int k = 0; k < 64; ++k)
        la[k * 65 + j] = logA_in[k * 64 + j];
    cfence();
    {   // exact op order (rounds 1..7 proven)
        float m = -1e30f;
#pragma unroll
        for (int k = 0; k < 64; ++k) m = fmaxf(m, la[j * 65 + k]);
        float s = 0.f;
#pragma unroll
        for (int k = 0; k < 64; ++k) s += expf(la[j * 65 + k] - m);
        rowlse[j] = m + logf(s);
    }
    cfence();
    {
        float v = logpi_in[j];
        float m = waveMax(v);
        float s = waveSum(expf(v - m));
        lpig[j] = v - (m + logf(s));
    }
    float4* o = (float4*)lAg;
#pragma unroll
    for (int k = 0; k < 16; ++k) {
        float4 v;
        v.x = la[(4 * k + 0) * 65 + j] - rowlse[4 * k + 0];
        v.y = la[(4 * k + 1) * 65 + j] - rowlse[4 * k + 1];
        v.z = la[(4 * k + 2) * 65 + j] - rowlse[4 * k + 2];
        v.w = la[(4 * k + 3) * 65 + j] - rowlse[4 * k + 3];
        o[j * 16 + k] = v;
    }
}

// ===== main: ONE wave handles BOTH chains (forward + viterbi) for batch b.
// Two independent recurrences interleaved for ILP; x-tile and lA column shared. =====
extern "C" __global__ __launch_bounds__(64, 1)
void hmm_main(const float* __restrict__ x,
              const float* __restrict__ means,
              const float* __restrict__ stds,
              const float* __restrict__ lAg,
              const float* __restrict__ lpig,
              float* __restrict__ out,
              float* __restrict__ dstore,
              int* __restrict__ c_last)
{
    __shared__ __align__(16) float xs[12304];     // x[b]: [t*6+d]
    __shared__ __align__(16) float fbuf[64];      // forward u (write-then-readback)
    __shared__ __align__(16) float vbuf[64];      // viterbi d

    const int j = threadIdx.x;
    const int b = blockIdx.x;

    // stage x once (shared by both chains; coalesced float4, same-wave in-order DS)
    {
        const float4* xg4 = (const float4*)(x + (size_t)b * T_LEN * 6);
        float4* xs4 = (float4*)xs;
        for (int i = j; i < 3075; i += 64) xs4[i] = xg4[i];
    }
    float lpi = lpig[j];

    // per-state emission constants
    float mu0 = means[j * 6 + 0], mu1 = means[j * 6 + 1];
    float mu2 = means[j * 6 + 2], mu3 = means[j * 6 + 3];
    float sg0 = fmaxf(stds[j * 6 + 0], 0.f) + 0.1f;
    float sg1 = fmaxf(stds[j * 6 + 1], 0.f) + 0.1f;
    float sg2 = fmaxf(stds[j * 6 + 2], 0.f) + 0.1f;
    float sg3 = fmaxf(stds[j * 6 + 3], 0.f) + 0.1f;
    float ls0 = logf(sg0), ls1 = logf(sg1), ls2 = logf(sg2), ls3 = logf(sg3);

    // column j of log_softmax(A): one load set, Ac derived in-regs
    float lA[64], Ac[64];
    {
        const float4* g = (const float4*)lAg;
#pragma unroll
        for (int k = 0; k < 16; ++k) {
            float4 v = g[j * 16 + k];
            lA[4 * k + 0] = v.x; lA[4 * k + 1] = v.y;
            lA[4 * k + 2] = v.z; lA[4 * k + 3] = v.w;
        }
#pragma unroll
        for (int k = 0; k < 64; ++k) Ac[k] = __expf(lA[k]);
    }
    float i0 = 1.f / sg0, i1 = 1.f / sg1, i2 = 1.f / sg2, i3 = 1.f / sg3;
    float cst = -(ls0 + ls1 + ls2 + ls3) - 4.f * HL2PI;

    const float4* fv = (const float4*)fbuf;
    const float4* vv = (const float4*)vbuf;

    // ---------------- prologue: t = 0 ----------------
    // forward (prob space; round-5/7 proven math)
    float z0 = (xs[0] - mu0) * i0, z1 = (xs[1] - mu1) * i1;
    float z2 = (xs[2] - mu2) * i2, z3 = (xs[3] - mu3) * i3;
    float a0 = (cst - 0.5f * (z0 * z0 + z1 * z1 + z2 * z2 + z3 * z3)) + lpi;
    float mm0 = dppMaxAll(a0);
    float u = __expf(a0 - mm0);
    fbuf[j] = u;
    // viterbi t=0 (exact reference op order, divisions)
    float v0 = (xs[0] - mu0) / sg0, v1 = (xs[1] - mu1) / sg1;
    float v2 = (xs[2] - mu2) / sg2, v3 = (xs[3] - mu3) / sg3;
    float e0 = ((-0.5f * v0) * v0 - ls0) - HL2PI;
    float e1 = ((-0.5f * v1) * v1 - ls1) - HL2PI;
    float e2 = ((-0.5f * v2) * v2 - ls2) - HL2PI;
    float e3 = ((-0.5f * v3) * v3 - ls3) - HL2PI;
    float dn = (((e0 + e1) + e2) + e3) + lpi;
    vbuf[j] = dn;

    float4 fr[16], vr[16];
#pragma unroll
    for (int k = 0; k < 16; ++k) fr[k] = fv[k];
#pragma unroll
    for (int k = 0; k < 16; ++k) vr[k] = vv[k];

    float s0 = dppSumAll(u);
    double acc = (double)(mm0 + __logf(s0));
    float rcp = 1.0f / s0;
    float* dp = dstore + (size_t)b * 64 + j;      // row t=0
    *dp = dn;

    // emissions for t = 1 (both forms from shared y)
    float lp_f, mm_c, e_c, lp_v;
    {
        float y0 = xs[6], y1 = xs[7], y2 = xs[8], y3 = xs[9];
        float w0 = (y0 - mu0) * i0, w1 = (y1 - mu1) * i1;
        float w2 = (y2 - mu2) * i2, w3 = (y3 - mu3) * i3;
        lp_f = cst - 0.5f * (w0 * w0 + w1 * w1 + w2 * w2 + w3 * w3);
        mm_c = dppMaxAll(lp_f);
        e_c  = __expf(lp_f - mm_c) * rcp;
        float q0 = (y0 - mu0) / sg0, q1 = (y1 - mu1) / sg1;
        float q2 = (y2 - mu2) / sg2, q3 = (y3 - mu3) / sg3;
        float f0 = ((-0.5f * q0) * q0 - ls0) - HL2PI;
        float f1 = ((-0.5f * q1) * q1 - ls1) - HL2PI;
        float f2 = ((-0.5f * q2) * q2 - ls2) - HL2PI;
        float f3 = ((-0.5f * q3) * q3 - ls3) - HL2PI;
        lp_v = ((f0 + f1) + f2) + f3;
    }

#pragma unroll 1
    for (int t = 1; t < T_LEN; ++t) {
        // next-emission xs reads issued first (drain during reduces)
        int o = ((t + 1 < T_LEN) ? (t + 1) : t) * 6;
        float y0 = xs[o], y1 = xs[o + 1], y2 = xs[o + 2], y3 = xs[o + 3];

        // viterbi reduce: best = max_i(d[i] + lA[i][j])  (4 independent chains; max assoc => bit-exact)
        float m0 = -3.4e38f, m1 = -3.4e38f, m2 = -3.4e38f, m3 = -3.4e38f;
#pragma unroll
        for (int k = 0; k < 16; ++k) {
            float4 dd = vr[k];
            m0 = fmaxf(m0, dd.x + lA[4 * k + 0]);
            m1 = fmaxf(m1, dd.y + lA[4 * k + 1]);
            m2 = fmaxf(m2, dd.z + lA[4 * k + 2]);
            m3 = fmaxf(m3, dd.w + lA[4 * k + 3]);
        }
        dn = fmaxf(fmaxf(m0, m1), fmaxf(m2, m3)) + lp_v;

        // forward reduce: q = sum_i u[i] * A[i][j]
        float q0 = 0.f, q1 = 0.f, q2 = 0.f, q3 = 0.f;
#pragma unroll
        for (int k = 0; k < 16; ++k) {
            float4 pp = fr[k];
            q0 = fmaf(pp.x, Ac[4 * k + 0], q0);
            q1 = fmaf(pp.y, Ac[4 * k + 1], q1);
            q2 = fmaf(pp.z, Ac[4 * k + 2], q2);
            q3 = fmaf(pp.w, Ac[4 * k + 3], q3);
        }
        u = ((q0 + q1) + (q2 + q3)) * e_c;

        // publish both, read back both (same-wave in-order LDS)
        vbuf[j] = dn;
        fbuf[j] = u;
#pragma unroll
        for (int k = 0; k < 16; ++k) vr[k] = vv[k];
#pragma unroll
        for (int k = 0; k < 16; ++k) fr[k] = fv[k];

        // work overlapping the in-flight reads:
        dp += B_SZ * 64;
        *dp = dn;                                   // d_t row (fire-and-forget)
        float s = dppSumAll(u);
        acc += (double)(mm_c + __logf(s));
        rcp = 1.0f / s;
        // forward emission t+1
        float w0 = (y0 - mu0) * i0, w1 = (y1 - mu1) * i1;
        float w2 = (y2 - mu2) * i2, w3 = (y3 - mu3) * i3;
        float lpn = cst - 0.5f * (w0 * w0 + w1 * w1 + w2 * w2 + w3 * w3);
        float mmn = dppMaxAll(lpn);
        e_c  = __expf(lpn - mmn) * rcp;
        mm_c = mmn;
        // viterbi emission t+1 (exact divisions)
        float x0 = (y0 - mu0) / sg0, x1 = (y1 - mu1) / sg1;
        float x2 = (y2 - mu2) / sg2, x3 = (y3 - mu3) / sg3;
        float f0 = ((-0.5f * x0) * x0 - ls0) - HL2PI;
        float f1 = ((-0.5f * x1) * x1 - ls1) - HL2PI;
        float f2 = ((-0.5f * x2) * x2 - ls2) - HL2PI;
        float f3 = ((-0.5f * x3) * x3 - ls3) - HL2PI;
        lp_v = ((f0 + f1) + f2) + f3;
    }

    if (j == 0) out[b] = (float)acc;
    float vvx = dn; int idx = j;
    waveArgmax(vvx, idx);
    if (j == 0) c_last[b] = idx;
}

// ===== psi recompute: persistent lA in regs, grid-stride over (t,b) pairs =====
extern "C" __global__ __launch_bounds__(256)
void hmm_psi(const float* __restrict__ dstore,
             const float* __restrict__ lAg,
             unsigned char* __restrict__ psi)
{
    __shared__ __align__(16) float sd[4][64];
    const int warp = threadIdx.x >> 6;
    const int j = threadIdx.x & 63;
    const int wid = blockIdx.x * 4 + warp;        // 0..8191

    float lA[64];
    {
        const float4* g = (const float4*)lAg;
#pragma unroll
        for (int k = 0; k < 16; ++k) {
            float4 v = g[j * 16 + k];
            lA[4 * k + 0] = v.x; lA[4 * k + 1] = v.y;
            lA[4 * k + 2] = v.z; lA[4 * k + 3] = v.w;
        }
    }
    const float4* dv = (const float4*)sd[warp];
    const int NP = 2049 * B_SZ;

    for (int p = wid; p < NP; p += 8192) {
        const int t = (p >> 7) + 1;
        const int b = p & 127;
        float dval = dstore[((size_t)(t - 1) * B_SZ + b) * 64 + j];
        sd[warp][j] = dval;    // same-wave in-order: reads below see it

        // round-5-verbatim argmax tracker (np.argmax first-occurrence semantics)
        float bv0 = -3.4e38f, bv1 = -3.4e38f, bv2 = -3.4e38f, bv3 = -3.4e38f;
        int bi0 = 0, bi1 = 1, bi2 = 2, bi3 = 3;
#pragma unroll
        for (int k = 0; k < 16; ++k) {
            float4 dd = dv[k];
            float v0 = dd.x + lA[4 * k + 0];
            float v1 = dd.y + lA[4 * k + 1];
            float v2 = dd.z + lA[4 * k + 2];
            float v3 = dd.w + lA[4 * k + 3];
            if (v0 > bv0) { bv0 = v0; bi0 = 4 * k + 0; }
            if (v1 > bv1) { bv1 = v1; bi1 = 4 * k + 1; }
            if (v2 > bv2) { bv2 = v2; bi2 = 4 * k + 2; }
            if (v3 > bv3) { bv3 = v3; bi3 = 4 * k + 3; }
        }
        float best = bv0; int bidx = bi0;
        if (bv1 > best || (bv1 == best && bi1 < bidx)) { best = bv1; bidx = bi1; }
        if (bv2 > best || (bv2 == best && bi2 < bidx)) { best = bv2; bidx = bi2; }
        if (bv3 > best || (bv3 == best && bi3 < bidx)) { best = bv3; bidx = bi3; }

        psi[((size_t)t * B_SZ + b) * 64 + j] = (unsigned char)bidx;
    }
}

// ===== per-chunk backpointer composition: wave per (b, g) =====
extern "C" __global__ __launch_bounds__(256)
void hmm_compose(const unsigned char* __restrict__ psi,
                 unsigned char* __restrict__ mt)
{
    const int w = blockIdx.x * 4 + (threadIdx.x >> 6);   // 0 .. 4223
    const int j = threadIdx.x & 63;
    const int g = w % NCHUNK;
    const int b = w / NCHUNK;
    const int e = (g < NCHUNK - 1) ? g * 64 + 64 : (T_LEN - 1);
    int M = j;
    for (int t = e; t >= g * 64 + 1; --t)
        M = psi[((size_t)t * B_SZ + b) * 64 + M];
    mt[((size_t)g * B_SZ + b) * 64 + j] = (unsigned char)M;
}

// ===== boundary walk + parallel chunk fill: block per batch =====
extern "C" __global__ __launch_bounds__(64, 1)
void hmm_fill(const unsigned char* __restrict__ psi,
              const unsigned char* __restrict__ mt,
              const int* __restrict__ c_last,
              float* __restrict__ out)
{
    __shared__ int sb[NCHUNK];       // sb[g] = state at t = 64*g
    const int b = blockIdx.x;
    const int g = threadIdx.x;
    const int cl = c_last[b];
    if (g == 0) {
        int cur = cl;
        for (int q = NCHUNK - 1; q >= 0; --q) {
            cur = mt[((size_t)q * B_SZ + b) * 64 + cur];
            sb[q] = cur;
        }
    }
    cfence();   // single wave, in-order DS
    float* oc = out + B_SZ + (size_t)b * T_LEN;
    if (g == NCHUNK) {
        oc[T_LEN - 1] = (float)cl;
    } else if (g < NCHUNK) {
        const int e = (g < NCHUNK - 1) ? g * 64 + 64 : (T_LEN - 1);
        int s = (g < NCHUNK - 1) ? sb[g + 1] : cl;
        for (int t = e; t >= g * 64 + 1; --t) {
            s = psi[((size_t)t * B_SZ + b) * 64 + s];
            oc[t - 1] = (float)s;
        }
    }
}

extern "C" void kernel_launch(void* const* d_in, const int* in_sizes, int n_in,
                              void* d_out, int out_size, void* d_ws, size_t ws_size,
                              hipStream_t stream)
{
    const float* x      = (const float*)d_in[0];
    const float* means  = (const float*)d_in[1];
    const float* stds   = (const float*)d_in[2];
    const float* logA   = (const float*)d_in[3];
    const float* logpi  = (const float*)d_in[4];
    float* out = (float*)d_out;

    // workspace layout (round-5/7 proven to fit)
    char* base = (char*)d_ws;
    float*         dstore = (float*)base;                                  // 67,174,400
    unsigned char* psi    = (unsigned char*)(base + 67174400);             // 16,793,600
    unsigned char* mt     = (unsigned char*)(base + 83968000);             //    270,336
    int*           cl     = (int*)(base + 84238336);                       //        512
    float*         lAg    = (float*)(base + 84238848);                     //     16,384
    float*         lpig   = (float*)(base + 84255232);                     //        256

    hipLaunchKernelGGL(hmm_prep, dim3(1), dim3(64), 0, stream, logA, logpi, lAg, lpig);
    hipLaunchKernelGGL(hmm_main, dim3(B_SZ), dim3(64), 0, stream,
                       x, means, stds, lAg, lpig, out, dstore, cl);
    hipLaunchKernelGGL(hmm_psi, dim3(2048), dim3(256), 0, stream, dstore, lAg, psi);
    hipLaunchKernelGGL(hmm_compose, dim3((NCHUNK * B_SZ) / 4), dim3(256), 0, stream, psi, mt);
    hipLaunchKernelGGL(hmm_fill, dim3(B_SZ), dim3(64), 0, stream, psi, mt, cl, out);
}

// Round 9
// 1059.314 us; speedup vs baseline: 1.7545x; 1.7545x over previous
//
#include <hip/hip_runtime.h>

#define T_LEN 2050
#define B_SZ 128
#define NCHUNK 33               // chunks of steps t=1..2049
#define HL2PI 0.91893853320467274178f

// ---------- wave-wide helpers (wave = 64 lanes) ----------
__device__ __forceinline__ float waveMax(float v) {
#pragma unroll
    for (int off = 32; off >= 1; off >>= 1)
        v = fmaxf(v, __shfl_xor(v, off, 64));
    return v;
}
__device__ __forceinline__ float waveSum(float v) {
#pragma unroll
    for (int off = 32; off >= 1; off >>= 1)
        v += __shfl_xor(v, off, 64);
    return v;
}
__device__ __forceinline__ void waveArgmax(float& v, int& idx) {
#pragma unroll
    for (int off = 32; off >= 1; off >>= 1) {
        float ov = __shfl_xor(v, off, 64);
        int   oi = __shfl_xor(idx, off, 64);
        if (ov > v || (ov == v && oi < idx)) { v = ov; idx = oi; }
    }
}
__device__ __forceinline__ void cfence() { asm volatile("" ::: "memory"); }

// DPP full-wave reductions (rounds 5-8 proven)
__device__ __forceinline__ float dppSumAll(float v) {
#define SSTEP(ctrl) { int t_ = __builtin_amdgcn_update_dpp(0, __float_as_int(v), ctrl, 0xf, 0xf, true); \
                      v = v + __int_as_float(t_); }
    SSTEP(0x111) SSTEP(0x112) SSTEP(0x114) SSTEP(0x118) SSTEP(0x142) SSTEP(0x143)
#undef SSTEP
    return __int_as_float(__builtin_amdgcn_readlane(__float_as_int(v), 63));
}
__device__ __forceinline__ float dppMaxAll(float v) {
#define MSTEP(ctrl) { int t_ = __builtin_amdgcn_update_dpp(__float_as_int(v), __float_as_int(v), ctrl, 0xf, 0xf, false); \
                      v = fmaxf(v, __int_as_float(t_)); }
    MSTEP(0x111) MSTEP(0x112) MSTEP(0x114) MSTEP(0x118) MSTEP(0x142) MSTEP(0x143)
#undef MSTEP
    return __int_as_float(__builtin_amdgcn_readlane(__float_as_int(v), 63));
}
__device__ __forceinline__ float rlane(int bits, int lane) {
    return __int_as_float(__builtin_amdgcn_readlane(bits, lane));
}

// ===== prep: log_softmax(log_A) -> lAg[c*64+i] (column-major), log_softmax(log_pi) =====
extern "C" __global__ __launch_bounds__(64, 1)
void hmm_prep(const float* __restrict__ logA_in,
              const float* __restrict__ logpi_in,
              float* __restrict__ lAg,
              float* __restrict__ lpig)
{
    __shared__ float la[64 * 65];
    __shared__ float rowlse[64];
    const int j = threadIdx.x;
#pragma unroll
    for (int k = 0; k < 64; ++k)
        la[k * 65 + j] = logA_in[k * 64 + j];
    cfence();
    {   // exact op order (rounds 1..8 proven)
        float m = -1e30f;
#pragma unroll
        for (int k = 0; k < 64; ++k) m = fmaxf(m, la[j * 65 + k]);
        float s = 0.f;
#pragma unroll
        for (int k = 0; k < 64; ++k) s += expf(la[j * 65 + k] - m);
        rowlse[j] = m + logf(s);
    }
    cfence();
    {
        float v = logpi_in[j];
        float m = waveMax(v);
        float s = waveSum(expf(v - m));
        lpig[j] = v - (m + logf(s));
    }
    float4* o = (float4*)lAg;
#pragma unroll
    for (int k = 0; k < 16; ++k) {
        float4 v;
        v.x = la[(4 * k + 0) * 65 + j] - rowlse[4 * k + 0];
        v.y = la[(4 * k + 1) * 65 + j] - rowlse[4 * k + 1];
        v.z = la[(4 * k + 2) * 65 + j] - rowlse[4 * k + 2];
        v.w = la[(4 * k + 3) * 65 + j] - rowlse[4 * k + 3];
        o[j * 16 + k] = v;
    }
}

// ===== emission precompute (EXACT op order, round-2 proven bit-exact) -> buf[b][t][64] =====
extern "C" __global__ __launch_bounds__(256)
void hmm_emis(const float* __restrict__ x,
              const float* __restrict__ means,
              const float* __restrict__ stds,
              float* __restrict__ buf)
{
    const int wid = blockIdx.x * 4 + (threadIdx.x >> 6);
    const int j = threadIdx.x & 63;
    const int t = wid >> 7;          // wid = t*128 + b
    const int b = wid & 127;

    const float* xt = x + ((size_t)b * T_LEN + t) * 6;
    float x0 = xt[0], x1 = xt[1], x2 = xt[2], x3 = xt[3];

    float mu0 = means[j * 6 + 0], mu1 = means[j * 6 + 1];
    float mu2 = means[j * 6 + 2], mu3 = means[j * 6 + 3];
    float sg0 = fmaxf(stds[j * 6 + 0], 0.f) + 0.1f;
    float sg1 = fmaxf(stds[j * 6 + 1], 0.f) + 0.1f;
    float sg2 = fmaxf(stds[j * 6 + 2], 0.f) + 0.1f;
    float sg3 = fmaxf(stds[j * 6 + 3], 0.f) + 0.1f;
    float ls0 = logf(sg0), ls1 = logf(sg1), ls2 = logf(sg2), ls3 = logf(sg3);

    float z0 = (x0 - mu0) / sg0, z1 = (x1 - mu1) / sg1;
    float z2 = (x2 - mu2) / sg2, z3 = (x3 - mu3) / sg3;
    float e0 = ((-0.5f * z0) * z0 - ls0) - HL2PI;
    float e1 = ((-0.5f * z1) * z1 - ls1) - HL2PI;
    float e2 = ((-0.5f * z2) * z2 - ls2) - HL2PI;
    float e3 = ((-0.5f * z3) * z3 - ls3) - HL2PI;
    float lp = ((e0 + e1) + e2) + e3;

    buf[((size_t)b * T_LEN + t) * 64 + j] = lp;
}

// ===== main: single wave per chain, readlane broadcast (no LDS in recurrence).
// blocks 0..127: forward -> out[b] (inline mul-path emission);
// blocks 128..255: viterbi -> d overwrites lp in buf (in-place), c_last =====
extern "C" __global__ __launch_bounds__(64, 1)
void hmm_main(const float* __restrict__ x,
              const float* __restrict__ means,
              const float* __restrict__ stds,
              const float* __restrict__ lAg,
              const float* __restrict__ lpig,
              float* __restrict__ out,
              float* __restrict__ buf,
              int* __restrict__ c_last)
{
    __shared__ __align__(16) float xs[12304];     // x[b] (forward half only)

    const int j   = threadIdx.x;
    const int bid = blockIdx.x;
    const bool is_fwd = (bid < B_SZ);
    const int b = is_fwd ? bid : bid - B_SZ;

    float lpi = lpig[j];

    if (is_fwd) {
        // stage x (forward computes emissions inline, mul path — rounds 5-7 proven)
        {
            const float4* xg4 = (const float4*)(x + (size_t)b * T_LEN * 6);
            float4* xs4 = (float4*)xs;
            for (int i = j; i < 3075; i += 64) xs4[i] = xg4[i];
        }
        float mu0 = means[j * 6 + 0], mu1 = means[j * 6 + 1];
        float mu2 = means[j * 6 + 2], mu3 = means[j * 6 + 3];
        float sg0 = fmaxf(stds[j * 6 + 0], 0.f) + 0.1f;
        float sg1 = fmaxf(stds[j * 6 + 1], 0.f) + 0.1f;
        float sg2 = fmaxf(stds[j * 6 + 2], 0.f) + 0.1f;
        float sg3 = fmaxf(stds[j * 6 + 3], 0.f) + 0.1f;
        float ls0 = logf(sg0), ls1 = logf(sg1), ls2 = logf(sg2), ls3 = logf(sg3);
        float i0 = 1.f / sg0, i1 = 1.f / sg1, i2 = 1.f / sg2, i3 = 1.f / sg3;
        float cst = -(ls0 + ls1 + ls2 + ls3) - 4.f * HL2PI;

        float Ac[64];
        {
            const float4* g = (const float4*)lAg;
#pragma unroll
            for (int k = 0; k < 16; ++k) {
                float4 v = g[j * 16 + k];
                Ac[4 * k + 0] = __expf(v.x); Ac[4 * k + 1] = __expf(v.y);
                Ac[4 * k + 2] = __expf(v.z); Ac[4 * k + 3] = __expf(v.w);
            }
        }
        cfence();   // xs staged (same-wave in-order DS)

        // t = 0
        float z0 = (xs[0] - mu0) * i0, z1 = (xs[1] - mu1) * i1;
        float z2 = (xs[2] - mu2) * i2, z3 = (xs[3] - mu3) * i3;
        float a0 = (cst - 0.5f * (z0 * z0 + z1 * z1 + z2 * z2 + z3 * z3)) + lpi;
        float m0a = dppMaxAll(a0);
        float u = __expf(a0 - m0a);
        float s0 = dppSumAll(u);
        double acc = (double)(m0a + __logf(s0));
        u *= (1.0f / s0);

        // pipeline emission for t = 1
        float mm_c, e_c;
        {
            float y0 = (xs[6] - mu0) * i0, y1 = (xs[7] - mu1) * i1;
            float y2 = (xs[8] - mu2) * i2, y3 = (xs[9] - mu3) * i3;
            float lp1 = cst - 0.5f * (y0 * y0 + y1 * y1 + y2 * y2 + y3 * y3);
            mm_c = dppMaxAll(lp1);
            e_c  = __expf(lp1 - mm_c);
        }

#pragma unroll 1
        for (int t = 1; t < T_LEN; ++t) {
            // next emission's xs reads issued early
            int o = ((t + 1 < T_LEN) ? (t + 1) : t) * 6;
            float y0 = xs[o], y1 = xs[o + 1], y2 = xs[o + 2], y3 = xs[o + 3];

            // broadcast u via readlane, reduce q = sum_i u[i]*A[i][j]
            int ub = __float_as_int(u);
            float q0 = 0.f, q1 = 0.f, q2 = 0.f, q3 = 0.f;
#pragma unroll
            for (int k = 0; k < 16; ++k) {
                q0 = fmaf(rlane(ub, 4 * k + 0), Ac[4 * k + 0], q0);
                q1 = fmaf(rlane(ub, 4 * k + 1), Ac[4 * k + 1], q1);
                q2 = fmaf(rlane(ub, 4 * k + 2), Ac[4 * k + 2], q2);
                q3 = fmaf(rlane(ub, 4 * k + 3), Ac[4 * k + 3], q3);
            }
            float q = (q0 + q1) + (q2 + q3);
            u = q * e_c;
            acc += (double)mm_c;
            if ((t & 3) == 0) {          // deferred renorm (telescoping sum, within slack)
                float ss = dppSumAll(u);
                acc += (double)__logf(ss);
                u *= (1.0f / ss);
            }

            // emission t+1 (mul path)
            float w0 = (y0 - mu0) * i0, w1 = (y1 - mu1) * i1;
            float w2 = (y2 - mu2) * i2, w3 = (y3 - mu3) * i3;
            float lpn = cst - 0.5f * (w0 * w0 + w1 * w1 + w2 * w2 + w3 * w3);
            float mmn = dppMaxAll(lpn);
            e_c  = __expf(lpn - mmn);
            mm_c = mmn;
        }
        float sf = dppSumAll(u);
        acc += (double)__logf(sf);
        if (j == 0) out[b] = (float)acc;
    } else {
        // ---------------- VITERBI: loaded exact lp, in-place d-over-lp, readlane reduce ----------------
        float lA[64];
        {
            const float4* g = (const float4*)lAg;
#pragma unroll
            for (int k = 0; k < 16; ++k) {
                float4 v = g[j * 16 + k];
                lA[4 * k + 0] = v.x; lA[4 * k + 1] = v.y;
                lA[4 * k + 2] = v.z; lA[4 * k + 3] = v.w;
            }
        }
        float* bb = buf + (size_t)b * T_LEN * 64 + j;   // row t at bb[t*64]

        // t = 0: read lp row 0, overwrite with d row 0
        float dn = bb[0] + lpi;
        // prefetch lp rows 1..4
        float l0 = bb[64], l1 = bb[128], l2 = bb[192], l3 = bb[256];
        bb[0] = dn;

#pragma unroll 1
        for (int t = 1; t < T_LEN; ++t) {
            float lp_c = l0; l0 = l1; l1 = l2; l2 = l3;
            int tp = t + 4; if (tp > T_LEN - 1) tp = T_LEN - 1;
            l3 = bb[(size_t)tp * 64];        // read t+4 (always before row t+4 is written)

            int db = __float_as_int(dn);
            float m0 = -3.4e38f, m1 = -3.4e38f, m2 = -3.4e38f, m3 = -3.4e38f;
#pragma unroll
            for (int k = 0; k < 8; ++k) {
                float t0 = rlane(db, 8 * k + 0) + lA[8 * k + 0];
                float t1 = rlane(db, 8 * k + 1) + lA[8 * k + 1];
                float t2 = rlane(db, 8 * k + 2) + lA[8 * k + 2];
                float t3 = rlane(db, 8 * k + 3) + lA[8 * k + 3];
                float t4 = rlane(db, 8 * k + 4) + lA[8 * k + 4];
                float t5 = rlane(db, 8 * k + 5) + lA[8 * k + 5];
                float t6 = rlane(db, 8 * k + 6) + lA[8 * k + 6];
                float t7 = rlane(db, 8 * k + 7) + lA[8 * k + 7];
                m0 = fmaxf(fmaxf(m0, t0), t1);   // max assoc: bit-exact
                m1 = fmaxf(fmaxf(m1, t2), t3);
                m2 = fmaxf(fmaxf(m2, t4), t5);
                m3 = fmaxf(fmaxf(m3, t6), t7);
            }
            float best = fmaxf(fmaxf(m0, m1), fmaxf(m2, m3));
            dn = best + lp_c;
            bb[(size_t)t * 64] = dn;            // overwrite lp row t with d row t
        }

        float vv = dn; int idx = j;
        waveArgmax(vv, idx);
        if (j == 0) c_last[b] = idx;
    }
}

// ===== psi recompute: persistent lA in regs, grid-stride over (t,b) pairs =====
extern "C" __global__ __launch_bounds__(256)
void hmm_psi(const float* __restrict__ buf,
             const float* __restrict__ lAg,
             unsigned char* __restrict__ psi)
{
    __shared__ __align__(16) float sd[4][64];
    const int warp = threadIdx.x >> 6;
    const int j = threadIdx.x & 63;
    const int wid = blockIdx.x * 4 + warp;        // 0..8191

    float lA[64];
    {
        const float4* g = (const float4*)lAg;
#pragma unroll
        for (int k = 0; k < 16; ++k) {
            float4 v = g[j * 16 + k];
            lA[4 * k + 0] = v.x; lA[4 * k + 1] = v.y;
            lA[4 * k + 2] = v.z; lA[4 * k + 3] = v.w;
        }
    }
    const float4* dv = (const float4*)sd[warp];
    const int NP = 2049 * B_SZ;

    for (int p = wid; p < NP; p += 8192) {
        const int t = (p >> 7) + 1;
        const int b = p & 127;
        float dval = buf[((size_t)b * T_LEN + (t - 1)) * 64 + j];
        sd[warp][j] = dval;    // same-wave in-order: reads below see it

        // round-5-verbatim argmax tracker (np.argmax first-occurrence semantics)
        float bv0 = -3.4e38f, bv1 = -3.4e38f, bv2 = -3.4e38f, bv3 = -3.4e38f;
        int bi0 = 0, bi1 = 1, bi2 = 2, bi3 = 3;
#pragma unroll
        for (int k = 0; k < 16; ++k) {
            float4 dd = dv[k];
            float v0 = dd.x + lA[4 * k + 0];
            float v1 = dd.y + lA[4 * k + 1];
            float v2 = dd.z + lA[4 * k + 2];
            float v3 = dd.w + lA[4 * k + 3];
            if (v0 > bv0) { bv0 = v0; bi0 = 4 * k + 0; }
            if (v1 > bv1) { bv1 = v1; bi1 = 4 * k + 1; }
            if (v2 > bv2) { bv2 = v2; bi2 = 4 * k + 2; }
            if (v3 > bv3) { bv3 = v3; bi3 = 4 * k + 3; }
        }
        float best = bv0; int bidx = bi0;
        if (bv1 > best || (bv1 == best && bi1 < bidx)) { best = bv1; bidx = bi1; }
        if (bv2 > best || (bv2 == best && bi2 < bidx)) { best = bv2; bidx = bi2; }
        if (bv3 > best || (bv3 == best && bi3 < bidx)) { best = bv3; bidx = bi3; }

        psi[((size_t)t * B_SZ + b) * 64 + j] = (unsigned char)bidx;
    }
}

// ===== per-chunk backpointer composition: wave per (b, g) =====
extern "C" __global__ __launch_bounds__(256)
void hmm_compose(const unsigned char* __restrict__ psi,
                 unsigned char* __restrict__ mt)
{
    const int w = blockIdx.x * 4 + (threadIdx.x >> 6);   // 0 .. 4223
    const int j = threadIdx.x & 63;
    const int g = w % NCHUNK;
    const int b = w / NCHUNK;
    const int e = (g < NCHUNK - 1) ? g * 64 + 64 : (T_LEN - 1);
    int M = j;
    for (int t = e; t >= g * 64 + 1; --t)
        M = psi[((size_t)t * B_SZ + b) * 64 + M];
    mt[((size_t)g * B_SZ + b) * 64 + j] = (unsigned char)M;
}

// ===== boundary walk + parallel chunk fill: block per batch =====
extern "C" __global__ __launch_bounds__(64, 1)
void hmm_fill(const unsigned char* __restrict__ psi,
              const unsigned char* __restrict__ mt,
              const int* __restrict__ c_last,
              float* __restrict__ out)
{
    __shared__ int sb[NCHUNK];       // sb[g] = state at t = 64*g
    const int b = blockIdx.x;
    const int g = threadIdx.x;
    const int cl = c_last[b];
    if (g == 0) {
        int cur = cl;
        for (int q = NCHUNK - 1; q >= 0; --q) {
            cur = mt[((size_t)q * B_SZ + b) * 64 + cur];
            sb[q] = cur;
        }
    }
    cfence();   // single wave, in-order DS
    float* oc = out + B_SZ + (size_t)b * T_LEN;
    if (g == NCHUNK) {
        oc[T_LEN - 1] = (float)cl;
    } else if (g < NCHUNK) {
        const int e = (g < NCHUNK - 1) ? g * 64 + 64 : (T_LEN - 1);
        int s = (g < NCHUNK - 1) ? sb[g + 1] : cl;
        for (int t = e; t >= g * 64 + 1; --t) {
            s = psi[((size_t)t * B_SZ + b) * 64 + s];
            oc[t - 1] = (float)s;
        }
    }
}

extern "C" void kernel_launch(void* const* d_in, const int* in_sizes, int n_in,
                              void* d_out, int out_size, void* d_ws, size_t ws_size,
                              hipStream_t stream)
{
    const float* x      = (const float*)d_in[0];
    const float* means  = (const float*)d_in[1];
    const float* stds   = (const float*)d_in[2];
    const float* logA   = (const float*)d_in[3];
    const float* logpi  = (const float*)d_in[4];
    float* out = (float*)d_out;

    // workspace: 84,255,488 B total (<= 85,022,208 proven available in round 2)
    char* base = (char*)d_ws;
    float*         buf  = (float*)base;                                  // 67,174,400 (lp then d, in place)
    unsigned char* psi  = (unsigned char*)(base + 67174400);             // 16,793,600
    unsigned char* mt   = (unsigned char*)(base + 83968000);             //    270,336
    int*           cl   = (int*)(base + 84238336);                       //        512
    float*         lAg  = (float*)(base + 84238848);                     //     16,384
    float*         lpig = (float*)(base + 84255232);                     //        256

    hipLaunchKernelGGL(hmm_prep, dim3(1), dim3(64), 0, stream, logA, logpi, lAg, lpig);
    hipLaunchKernelGGL(hmm_emis, dim3((T_LEN * B_SZ) / 4), dim3(256), 0, stream,
                       x, means, stds, buf);
    hipLaunchKernelGGL(hmm_main, dim3(2 * B_SZ), dim3(64), 0, stream,
                       x, means, stds, lAg, lpig, out, buf, cl);
    hipLaunchKernelGGL(hmm_psi, dim3(2048), dim3(256), 0, stream, buf, lAg, psi);
    hipLaunchKernelGGL(hmm_compose, dim3((NCHUNK * B_SZ) / 4), dim3(256), 0, stream, psi, mt);
    hipLaunchKernelGGL(hmm_fill, dim3(B_SZ), dim3(64), 0, stream, psi, mt, cl, out);
}